// Round 3
// baseline (218.353 us; speedup 1.0000x reference)
//
#include <hip/hip_runtime.h>

#define C_ 512
#define L_ 784
#define K_ 64
#define EPS_ 1e-12f

typedef _Float16 half_t;
typedef _Float16 half4 __attribute__((ext_vector_type(4)));
typedef float float4v __attribute__((ext_vector_type(4)));

// ---------------------------------------------------------------------------
// kF v3: ZERO-STAGING fused logits -> softmax -> partial agg.
// grid (4, 64), block 1024 (16 waves = 4 kt x 4 cs). LDS = 19 KB (sl + ah only).
//
// All x fragments are per-lane dwordx4 loads straight from global (L1/L2-hot;
// the 4 kt-waves of a cs read identical 32KB windows -> L1 absorbs).
// Loaded fragment S: lane m16 = c-row (of 16-c tile), kk = q*4+j = l.
//   - agg B-operand: S used directly:   B[kk=l][n=c]            (K=16)
//   - logits A-operand: one identity-MFMA transposes S:
//       T = mfma_16x16x16f16(S, I, 0)  => lane m16 = l, reg r -> c = 4q+r
//     which IS the A-frag layout (m=l, kk=q*4+j -> c). f16->f32->f16 exact.
// Per 16-l subtile s:
//   1. 8x { load dwordx4, cvt -> bh[i]; T = mfma(bh[i], I); a4 = cvt(T);
//           lac += mfma(a4, wf[i]) }                   // D[l][k] logits
//   2. sl[l][k][cs] = lac; barrier A
//   3. softmax: wave=l-row, lane=k, shfl_xor trees; ah[k][l] fp16; barrier B
//   4. agg: agc[i] += mfma(A=ah, B=bh[i])              // D[k][c], K=16
// MFMA 16x16x16f16 maps: A: m=lane&15, kk=q*4+j; B: n=lane&15, kk=q*4+j;
// D: row=q*4+r, col=lane&15 (same family as the verified 16x16x32 maps).
// ---------------------------------------------------------------------------
__global__ __launch_bounds__(1024, 4) void kF(const float* __restrict__ x,
                                              const float* __restrict__ w,
                                              float* __restrict__ aggP,
                                              float* __restrict__ asumP) {
    __shared__ float  sl[16 * 64 * 4];  // [l][k][cs] logits partials (16 KB)
    __shared__ half_t ah[64 * 20];      // a fp16 [k][16 l + pad4] (2.5 KB)

    const int t    = threadIdx.x;
    const int n    = blockIdx.y;
    const int bx   = blockIdx.x;
    const int l0   = bx * 192;
    const int NT   = (bx == 3) ? 13 : 12;
    const int wv   = t >> 6;
    const int lane = t & 63;
    const int m16  = lane & 15;
    const int q    = lane >> 4;
    const int kt   = wv & 3;   // k-tile (16 k)
    const int cs   = wv >> 2;  // c-segment (128 c = 8 tiles of 16)

    const float* xn = x + (size_t)n * (C_ * L_);

    // w fragments (B-style): lane n16 -> k row, elems j -> c = cs*128+i*16+4q+j
    half4 wf[8];
#pragma unroll
    for (int i = 0; i < 8; ++i) {
        float4v f = *(const float4v*)(w + (size_t)(kt * 16 + m16) * C_ +
                                      cs * 128 + i * 16 + 4 * q);
        wf[i] = half4{(half_t)f[0], (half_t)f[1], (half_t)f[2], (half_t)f[3]};
    }
    // identity B-fragment: I[kk=4q+j][n=m16]
    half4 ifr;
#pragma unroll
    for (int j = 0; j < 4; ++j) ifr[j] = (half_t)((4 * q + j == m16) ? 1.0f : 0.0f);

    const float4v z4 = {0.f, 0.f, 0.f, 0.f};
    float4v agc[8];
#pragma unroll
    for (int i = 0; i < 8; ++i) agc[i] = z4;
    float asum_reg = 0.f;

    for (int s = 0; s < NT; ++s) {
        const int ls = l0 + 16 * s;
        half4 bh[8];
        float4v lac0 = z4, lac1 = z4;
#pragma unroll
        for (int i = 0; i < 8; ++i) {
            float4v xq = *(const float4v*)(xn + (size_t)((cs * 8 + i) * 16 + m16) * L_ +
                                           ls + 4 * q);
            half4 s4 = {(half_t)xq[0], (half_t)xq[1], (half_t)xq[2], (half_t)xq[3]};
            bh[i] = s4;
            // transpose via identity-MFMA: lane m16 -> l, reg r -> c = 4q+r
            float4v xt = __builtin_amdgcn_mfma_f32_16x16x16f16(s4, ifr, z4, 0, 0, 0);
            half4 a4 = {(half_t)xt[0], (half_t)xt[1], (half_t)xt[2], (half_t)xt[3]};
            if (i < 4) lac0 = __builtin_amdgcn_mfma_f32_16x16x16f16(a4, wf[i], lac0, 0, 0, 0);
            else       lac1 = __builtin_amdgcn_mfma_f32_16x16x16f16(a4, wf[i], lac1, 0, 0, 0);
        }
        float4v lac = lac0 + lac1;
        // D[l][k]: row 4q+r = l_local, col m16 = k_local
#pragma unroll
        for (int r = 0; r < 4; ++r)
            sl[((4 * q + r) * 64 + kt * 16 + m16) * 4 + cs] = lac[r];
        __syncthreads();   // barrier A
        // softmax: wave wv = l-row, lane = k (all 1024 threads active)
        {
            float4v p4 = *(const float4v*)&sl[(wv * 64 + lane) * 4];
            float lg = p4[0] + p4[1] + p4[2] + p4[3];
            float mx = lg;
#pragma unroll
            for (int off = 32; off; off >>= 1) mx = fmaxf(mx, __shfl_xor(mx, off, 64));
            float e = __expf(lg - mx);
            float sm = e;
#pragma unroll
            for (int off = 32; off; off >>= 1) sm += __shfl_xor(sm, off, 64);
            float a = e / sm;
            asum_reg += a;
            ah[lane * 20 + wv] = (half_t)a;
        }
        __syncthreads();   // barrier B
        // agg: D[k][c] += a[k][l] * x[c][l], K=16 (this subtile's l window)
        half4 aA = *(const half4*)&ah[(kt * 16 + m16) * 20 + 4 * q];
#pragma unroll
        for (int i = 0; i < 8; ++i)
            agc[i] = __builtin_amdgcn_mfma_f32_16x16x16f16(aA, bh[i], agc[i], 0, 0, 0);
    }

    // ---- epilogue: asum reduce (sl reused) + direct coalesced agg stores ----
    sl[wv * 64 + lane] = asum_reg;
    __syncthreads();
    if (t < 64) {
        float s_ = 0.f;
#pragma unroll
        for (int j = 0; j < 16; ++j) s_ += sl[j * 64 + t];
        asumP[((size_t)n * 4 + bx) * 64 + t] = s_;
    }
    float* ap = aggP + (((size_t)n * 4 + bx) * 64) * (size_t)C_;
#pragma unroll
    for (int i = 0; i < 8; ++i)
#pragma unroll
        for (int r = 0; r < 4; ++r)
            ap[(size_t)(kt * 16 + 4 * q + r) * C_ + (cs * 8 + i) * 16 + m16] = agc[i][r];
}

// ---------------------------------------------------------------------------
// kC: reduce 4 agg partials, vlad = agg - asum*cent, intra-normalize per
// (n,k) over C; global norm is exactly 8 (64 unit rows).  grid (8,64), 256.
// float4-vectorized loads/stores (safely BW-bound).
// ---------------------------------------------------------------------------
__global__ __launch_bounds__(256) void kC(const float* __restrict__ aggP,
                                          const float* __restrict__ cent,
                                          const float* __restrict__ asumP,
                                          float* __restrict__ out) {
    __shared__ float asumS[8];
    const int t  = threadIdx.x;
    const int n  = blockIdx.y;
    const int k0 = blockIdx.x * 8;
    if (t < 8) {
        float s = 0.f;
        for (int j = 0; j < 4; ++j) s += asumP[((size_t)n * 4 + j) * 64 + k0 + t];
        asumS[t] = s;
    }
    __syncthreads();
    const int wv   = t >> 6;
    const int lane = t & 63;
    for (int r = wv; r < 8; r += 4) {
        const int k = k0 + r;
        const float as = asumS[r];
        const float* a0 = aggP + (((size_t)n * 4 + 0) * 64 + k) * C_;
        const float* a1 = aggP + (((size_t)n * 4 + 1) * 64 + k) * C_;
        const float* a2 = aggP + (((size_t)n * 4 + 2) * 64 + k) * C_;
        const float* a3 = aggP + (((size_t)n * 4 + 3) * 64 + k) * C_;
        const float* cp = cent + (size_t)k * C_;
        float4v v[2];
        float ss = 0.f;
#pragma unroll
        for (int j = 0; j < 2; ++j) {
            const int c = 4 * lane + 256 * j;
            float4v val = *(const float4v*)(a0 + c);
            val = val + *(const float4v*)(a1 + c);
            val = val + *(const float4v*)(a2 + c);
            val = val + *(const float4v*)(a3 + c);
            float4v c4 = *(const float4v*)(cp + c);
#pragma unroll
            for (int e = 0; e < 4; ++e) {
                val[e] -= as * c4[e];
                ss += val[e] * val[e];
            }
            v[j] = val;
        }
#pragma unroll
        for (int off = 32; off; off >>= 1) ss += __shfl_xor(ss, off, 64);
        const float scale = 1.f / (fmaxf(sqrtf(ss), EPS_) * 8.f);
        float* op = out + (size_t)n * (K_ * C_) + (size_t)k * C_;
#pragma unroll
        for (int j = 0; j < 2; ++j) {
            float4v o = v[j];
#pragma unroll
            for (int e = 0; e < 4; ++e) o[e] *= scale;
            *(float4v*)(op + 4 * lane + 256 * j) = o;
        }
    }
}

extern "C" void kernel_launch(void* const* d_in, const int* in_sizes, int n_in,
                              void* d_out, int out_size, void* d_ws, size_t ws_size,
                              hipStream_t stream) {
    (void)in_sizes; (void)n_in; (void)out_size; (void)ws_size;
    const float* x    = (const float*)d_in[0];   // (64, 512, 28, 28) fp32
    const float* w    = (const float*)d_in[1];   // (64, 512) fp32
    const float* cent = (const float*)d_in[2];   // (64, 512) fp32
    float* out = (float*)d_out;                  // (64, 32768) fp32

    // ws: aggP f32 [64 n][4 bx][64 k][512 c] = 33.6 MB ; asumP f32 [64][4][64]
    // = 64 KB.  Total 33.7 MB (ws_size >= 46 MB known-good).
    char* base = (char*)d_ws;
    float* aggP  = (float*)base;
    float* asumP = aggP + (size_t)64 * 4 * 64 * 512;

    kF<<<dim3(4, 64), 1024, 0, stream>>>(x, w, aggP, asumP);
    kC<<<dim3(8, 64), 256, 0, stream>>>(aggP, cent, asumP, out);
}

// Round 4
// 179.312 us; speedup vs baseline: 1.2177x; 1.2177x over previous
//
#include <hip/hip_runtime.h>

#define C_ 512
#define L_ 784
#define K_ 64
#define EPS_ 1e-12f

typedef _Float16 half_t;
typedef _Float16 half4 __attribute__((ext_vector_type(4)));
typedef float float4v __attribute__((ext_vector_type(4)));

// ---------------------------------------------------------------------------
// kF v4: zero-staging fused logits -> softmax -> partial agg, WITH register
// software-pipelining (the thing r3 lost vs r2).
// grid (4, 64), block 1024 (16 waves = 4 kt x 4 cs). LDS = 19 KB (sl + ah).
//
// Per 16-l subtile s:
//   0. bh[i] = cvt(pf[i])            // x frags staged LAST subtile
//   1. issue pf[i] loads for s+1     // full subtile of latency cover
//   2. logits: T = mfma(bh[i], I) transpose; lac += mfma(T_h, wf[i])
//   3. sl[l][k][cs] partials; barrier A
//   4. softmax: wave=l-row, lane=k, shfl_xor trees; ah[k][l]; barrier B
//   5. agg: agc[i] += mfma(A=ah, B=bh[i])   // K=16, bh reused from regs
// MFMA maps verified end-to-end in r3 (passed, absmax 1.2e-4):
//   A: m=lane&15, kk=q*4+j; B: n=lane&15, kk=q*4+j; D: row=q*4+r, col=lane&15.
// VGPR budget: pf 32 + agc 32 + bh 16 + wf 16 + misc ~20 ~= 118 < 128 cap
// (1024-thr block forces 4 waves/SIMD). NO min-occupancy bound: r3's
// (1024,4) yielded VGPR=56 and serialized loads.
// ---------------------------------------------------------------------------
__global__ __launch_bounds__(1024) void kF(const float* __restrict__ x,
                                           const float* __restrict__ w,
                                           float* __restrict__ aggP,
                                           float* __restrict__ asumP) {
    __shared__ float  sl[16 * 64 * 4];  // [l][k][cs] logits partials (16 KB)
    __shared__ half_t ah[64 * 20];      // a fp16 [k][16 l + pad4] (2.5 KB)

    const int t    = threadIdx.x;
    const int n    = blockIdx.y;
    const int bx   = blockIdx.x;
    const int l0   = bx * 192;
    const int NT   = (bx == 3) ? 13 : 12;
    const int wv   = t >> 6;
    const int lane = t & 63;
    const int m16  = lane & 15;
    const int q    = lane >> 4;
    const int kt   = wv & 3;   // k-tile (16 k)
    const int cs   = wv >> 2;  // c-segment (128 c = 8 tiles of 16)

    const float* xn = x + (size_t)n * (C_ * L_);
    // this lane's x row base: row (cs*8+i)*16+m16, col l0+4q; row i at +i*16*L_
    const float* xr = xn + (size_t)(cs * 128 + m16) * L_ + l0 + 4 * q;

    // prefetch subtile 0 (issued before anything else: max latency cover)
    float4v pf[8];
#pragma unroll
    for (int i = 0; i < 8; ++i)
        pf[i] = *(const float4v*)(xr + (size_t)i * 16 * L_);

    // w fragments (B-style): lane m16 -> k row, elems j -> c = cs*128+i*16+4q+j
    half4 wf[8];
#pragma unroll
    for (int i = 0; i < 8; ++i) {
        float4v f = *(const float4v*)(w + (size_t)(kt * 16 + m16) * C_ +
                                      cs * 128 + i * 16 + 4 * q);
        wf[i] = half4{(half_t)f[0], (half_t)f[1], (half_t)f[2], (half_t)f[3]};
    }
    // identity B-fragment: I[kk=4q+j][n=m16]
    half4 ifr;
#pragma unroll
    for (int j = 0; j < 4; ++j) ifr[j] = (half_t)((4 * q + j == m16) ? 1.0f : 0.0f);

    const float4v z4 = {0.f, 0.f, 0.f, 0.f};
    float4v agc[8];
#pragma unroll
    for (int i = 0; i < 8; ++i) agc[i] = z4;
    float asum_reg = 0.f;

    for (int s = 0; s < NT; ++s) {
        // 0. convert the staged fragments for THIS subtile (data long arrived)
        half4 bh[8];
#pragma unroll
        for (int i = 0; i < 8; ++i)
            bh[i] = half4{(half_t)pf[i][0], (half_t)pf[i][1],
                          (half_t)pf[i][2], (half_t)pf[i][3]};
        // 1. issue next-subtile loads; consumed only at next iteration's cvt
        if (s + 1 < NT) {
            const float* p = xr + (s + 1) * 16;
#pragma unroll
            for (int i = 0; i < 8; ++i)
                pf[i] = *(const float4v*)(p + (size_t)i * 16 * L_);
        }
        // 2. logits: transpose via identity-MFMA, then accumulate vs w
        float4v lac0 = z4, lac1 = z4;
#pragma unroll
        for (int i = 0; i < 8; ++i) {
            float4v xt = __builtin_amdgcn_mfma_f32_16x16x16f16(bh[i], ifr, z4, 0, 0, 0);
            half4 a4 = {(half_t)xt[0], (half_t)xt[1], (half_t)xt[2], (half_t)xt[3]};
            if (i < 4) lac0 = __builtin_amdgcn_mfma_f32_16x16x16f16(a4, wf[i], lac0, 0, 0, 0);
            else       lac1 = __builtin_amdgcn_mfma_f32_16x16x16f16(a4, wf[i], lac1, 0, 0, 0);
        }
        float4v lac = lac0 + lac1;
        // 3. D[l][k]: row 4q+r = l_local, col m16 = k_local
#pragma unroll
        for (int r = 0; r < 4; ++r)
            sl[((4 * q + r) * 64 + kt * 16 + m16) * 4 + cs] = lac[r];
        __syncthreads();   // barrier A
        // 4. softmax: wave wv = l-row, lane = k (all 1024 threads active)
        {
            float4v p4 = *(const float4v*)&sl[(wv * 64 + lane) * 4];
            float lg = p4[0] + p4[1] + p4[2] + p4[3];
            float mx = lg;
#pragma unroll
            for (int off = 32; off; off >>= 1) mx = fmaxf(mx, __shfl_xor(mx, off, 64));
            float e = __expf(lg - mx);
            float sm = e;
#pragma unroll
            for (int off = 32; off; off >>= 1) sm += __shfl_xor(sm, off, 64);
            float a = e / sm;
            asum_reg += a;
            ah[lane * 20 + wv] = (half_t)a;
        }
        __syncthreads();   // barrier B
        // 5. agg: D[k][c] += a[k][l] * x[c][l], K=16, bh straight from regs
        half4 aA = *(const half4*)&ah[(kt * 16 + m16) * 20 + 4 * q];
#pragma unroll
        for (int i = 0; i < 8; ++i)
            agc[i] = __builtin_amdgcn_mfma_f32_16x16x16f16(aA, bh[i], agc[i], 0, 0, 0);
    }

    // ---- epilogue: asum reduce (sl reused) + direct coalesced agg stores ----
    sl[wv * 64 + lane] = asum_reg;
    __syncthreads();
    if (t < 64) {
        float s_ = 0.f;
#pragma unroll
        for (int j = 0; j < 16; ++j) s_ += sl[j * 64 + t];
        asumP[((size_t)n * 4 + bx) * 64 + t] = s_;
    }
    float* ap = aggP + (((size_t)n * 4 + bx) * 64) * (size_t)C_;
#pragma unroll
    for (int i = 0; i < 8; ++i)
#pragma unroll
        for (int r = 0; r < 4; ++r)
            ap[(size_t)(kt * 16 + 4 * q + r) * C_ + (cs * 8 + i) * 16 + m16] = agc[i][r];
}

// ---------------------------------------------------------------------------
// kC v2: reduce 4 agg partials, vlad = agg - asum*cent, intra-normalize per
// (n,k) over C; global norm is exactly 8.  grid (16,64) = 1024 blocks (vs 512
// before: kC was latency-bound at 2 waves/SIMD), 256 thr, ONE k-row per wave.
// ---------------------------------------------------------------------------
__global__ __launch_bounds__(256) void kC(const float* __restrict__ aggP,
                                          const float* __restrict__ cent,
                                          const float* __restrict__ asumP,
                                          float* __restrict__ out) {
    __shared__ float asumS[4];
    const int t  = threadIdx.x;
    const int n  = blockIdx.y;
    const int k0 = blockIdx.x * 4;
    if (t < 4) {
        float s = 0.f;
        for (int j = 0; j < 4; ++j) s += asumP[((size_t)n * 4 + j) * 64 + k0 + t];
        asumS[t] = s;
    }
    __syncthreads();
    const int wv   = t >> 6;
    const int lane = t & 63;
    const int k    = k0 + wv;
    const float as = asumS[wv];
    const float* a0 = aggP + (((size_t)n * 4 + 0) * 64 + k) * C_;
    const float* a1 = aggP + (((size_t)n * 4 + 1) * 64 + k) * C_;
    const float* a2 = aggP + (((size_t)n * 4 + 2) * 64 + k) * C_;
    const float* a3 = aggP + (((size_t)n * 4 + 3) * 64 + k) * C_;
    const float* cp = cent + (size_t)k * C_;
    float4v v[2];
    float ss = 0.f;
#pragma unroll
    for (int j = 0; j < 2; ++j) {
        const int c = 4 * lane + 256 * j;
        float4v val = *(const float4v*)(a0 + c);
        val = val + *(const float4v*)(a1 + c);
        val = val + *(const float4v*)(a2 + c);
        val = val + *(const float4v*)(a3 + c);
        float4v c4 = *(const float4v*)(cp + c);
#pragma unroll
        for (int e = 0; e < 4; ++e) {
            val[e] -= as * c4[e];
            ss += val[e] * val[e];
        }
        v[j] = val;
    }
#pragma unroll
    for (int off = 32; off; off >>= 1) ss += __shfl_xor(ss, off, 64);
    const float scale = 1.f / (fmaxf(sqrtf(ss), EPS_) * 8.f);
    float* op = out + (size_t)n * (K_ * C_) + (size_t)k * C_;
#pragma unroll
    for (int j = 0; j < 2; ++j) {
        float4v o = v[j];
#pragma unroll
        for (int e = 0; e < 4; ++e) o[e] *= scale;
        *(float4v*)(op + 4 * lane + 256 * j) = o;
    }
}

extern "C" void kernel_launch(void* const* d_in, const int* in_sizes, int n_in,
                              void* d_out, int out_size, void* d_ws, size_t ws_size,
                              hipStream_t stream) {
    (void)in_sizes; (void)n_in; (void)out_size; (void)ws_size;
    const float* x    = (const float*)d_in[0];   // (64, 512, 28, 28) fp32
    const float* w    = (const float*)d_in[1];   // (64, 512) fp32
    const float* cent = (const float*)d_in[2];   // (64, 512) fp32
    float* out = (float*)d_out;                  // (64, 32768) fp32

    // ws: aggP f32 [64 n][4 bx][64 k][512 c] = 33.6 MB ; asumP f32 [64][4][64]
    // = 64 KB.  Total 33.7 MB (ws_size >= 46 MB known-good).
    char* base = (char*)d_ws;
    float* aggP  = (float*)base;
    float* asumP = aggP + (size_t)64 * 4 * 64 * 512;

    kF<<<dim3(4, 64), 1024, 0, stream>>>(x, w, aggP, asumP);
    kC<<<dim3(16, 64), 256, 0, stream>>>(aggP, cent, asumP, out);
}